// Round 1
// baseline (986.487 us; speedup 1.0000x reference)
//
#include <hip/hip_runtime.h>
#include <hip/hip_bf16.h>

typedef __bf16 bf8 __attribute__((ext_vector_type(8)));
typedef float f4 __attribute__((ext_vector_type(4)));
typedef unsigned short u16;

#define B_ 4
#define P_ 2048
#define D_ 768
#define H_ 12
#define HD_ 64
#define SCALE_ 0.125f

__device__ __forceinline__ u16 f2bf(float f) {
  union { float f; unsigned u; } c; c.f = f;
  unsigned u = c.u;
  u += 0x7fffu + ((u >> 16) & 1u);
  return (u16)(u >> 16);
}

__device__ __forceinline__ f4 mfma16(bf8 a, bf8 b, f4 c) {
  return __builtin_amdgcn_mfma_f32_16x16x32_bf16(a, b, c, 0, 0, 0);
}

// ---------------- transpose-cast fp32 (R,C) -> bf16 (C,R) ----------------
__global__ __launch_bounds__(256) void tcast_k(const float* __restrict__ src,
                                               u16* __restrict__ dst, int R, int C) {
  __shared__ float t[32][33];
  int c0 = blockIdx.x * 32, r0 = blockIdx.y * 32;
  int tx = threadIdx.x & 31, ty = threadIdx.x >> 5;  // 32 x 8
  #pragma unroll
  for (int i = 0; i < 32; i += 8) {
    int r = r0 + ty + i, c = c0 + tx;
    t[ty + i][tx] = (r < R && c < C) ? src[(size_t)r * C + c] : 0.f;
  }
  __syncthreads();
  #pragma unroll
  for (int i = 0; i < 32; i += 8) {
    int c = c0 + ty + i, r = r0 + tx;
    if (c < C && r < R) dst[(size_t)c * R + r] = f2bf(t[tx][ty + i]);
  }
}

// ---------------- layernorm fp32 -> bf16, one row (768) per block ----------------
__global__ __launch_bounds__(256) void ln_k(const float* __restrict__ x,
                                            const float* __restrict__ g,
                                            const float* __restrict__ b,
                                            u16* __restrict__ out) {
  int row = blockIdx.x;
  const float* xr = x + (size_t)row * D_;
  float v0 = xr[threadIdx.x], v1 = xr[threadIdx.x + 256], v2 = xr[threadIdx.x + 512];
  float s = v0 + v1 + v2;
  float s2 = v0 * v0 + v1 * v1 + v2 * v2;
  #pragma unroll
  for (int o = 32; o > 0; o >>= 1) {
    s += __shfl_down(s, o, 64);
    s2 += __shfl_down(s2, o, 64);
  }
  __shared__ float a[4], a2[4];
  int wv = threadIdx.x >> 6;
  if ((threadIdx.x & 63) == 0) { a[wv] = s; a2[wv] = s2; }
  __syncthreads();
  s = a[0] + a[1] + a[2] + a[3];
  s2 = a2[0] + a2[1] + a2[2] + a2[3];
  float mean = s * (1.f / 768.f);
  float var = s2 * (1.f / 768.f) - mean * mean;
  float rstd = rsqrtf(var + 1e-5f);
  u16* orow = out + (size_t)row * D_;
  float vv[3] = {v0, v1, v2};
  #pragma unroll
  for (int j = 0; j < 3; ++j) {
    int i = threadIdx.x + j * 256;
    orow[i] = f2bf((vv[j] - mean) * rstd * g[i] + b[i]);
  }
}

// ---------------- wave-level 64x64 GEMM core: C += A(M,K) * Bt(N,K)^T ----------------
template <int K>
__device__ __forceinline__ void wave_gemm(const u16* __restrict__ A, int lda,
                                          const u16* __restrict__ Bt, int ldb,
                                          f4 acc[4][4]) {
  const int lane = threadIdx.x & 63, l15 = lane & 15, quad = lane >> 4;
  #pragma unroll 2
  for (int k = 0; k < K; k += 32) {
    bf8 a[4], b[4];
    #pragma unroll
    for (int mt = 0; mt < 4; ++mt)
      a[mt] = *reinterpret_cast<const bf8*>(A + (size_t)(mt * 16 + l15) * lda + k + quad * 8);
    #pragma unroll
    for (int nt = 0; nt < 4; ++nt)
      b[nt] = *reinterpret_cast<const bf8*>(Bt + (size_t)(nt * 16 + l15) * ldb + k + quad * 8);
    #pragma unroll
    for (int mt = 0; mt < 4; ++mt)
      #pragma unroll
      for (int nt = 0; nt < 4; ++nt)
        acc[mt][nt] = mfma16(a[mt], b[nt], acc[mt][nt]);
  }
}

#define ZERO44(acc)                    \
  {                                    \
    f4 z_ = {0.f, 0.f, 0.f, 0.f};      \
    for (int i_ = 0; i_ < 4; ++i_)     \
      for (int j_ = 0; j_ < 4; ++j_)   \
        acc[i_][j_] = z_;              \
  }

// ---------------- QKV GEMM: hln(8192,768) @ wT(2304,768)^T + bias -> Q,K,(V^T) bf16 ----------------
__global__ __launch_bounds__(256) void gemm_qkv_k(const u16* __restrict__ hln,
                                                  const u16* __restrict__ wT,
                                                  const float* __restrict__ bias,
                                                  u16* __restrict__ Q, u16* __restrict__ Km,
                                                  u16* __restrict__ Vt) {
  int wave = threadIdx.x >> 6;
  int m0 = blockIdx.y * 128 + (wave & 1) * 64;
  int n0 = blockIdx.x * 128 + (wave >> 1) * 64;
  f4 acc[4][4];
  ZERO44(acc);
  wave_gemm<768>(hln + (size_t)m0 * 768, 768, wT + (size_t)n0 * 768, 768, acc);
  int lane = threadIdx.x & 63, l15 = lane & 15, quad = lane >> 4;
  #pragma unroll
  for (int mt = 0; mt < 4; ++mt)
    #pragma unroll
    for (int nt = 0; nt < 4; ++nt)
      #pragma unroll
      for (int r = 0; r < 4; ++r) {
        int m = m0 + mt * 16 + quad * 4 + r;
        int n = n0 + nt * 16 + l15;
        float v = acc[mt][nt][r] + bias[n];
        u16 bv = f2bf(v);
        int b = m >> 11, p = m & 2047;
        int which = n / 768, hn = n % 768;
        int h = hn >> 6, d = hn & 63;
        if (which == 0)
          Q[((size_t)(b * H_ + h) * P_ + p) * HD_ + d] = bv;
        else if (which == 1)
          Km[((size_t)(b * H_ + h) * P_ + p) * HD_ + d] = bv;
        else
          Vt[((size_t)(b * H_ + h) * HD_ + d) * P_ + p] = bv;
      }
}

// ---------------- FC1 GEMM + exact GELU -> bf16 (8192,3072) ----------------
__global__ __launch_bounds__(256) void gemm_fc1_k(const u16* __restrict__ A,
                                                  const u16* __restrict__ wT,
                                                  const float* __restrict__ bias,
                                                  u16* __restrict__ out) {
  int wave = threadIdx.x >> 6;
  int m0 = blockIdx.y * 128 + (wave & 1) * 64;
  int n0 = blockIdx.x * 128 + (wave >> 1) * 64;
  f4 acc[4][4];
  ZERO44(acc);
  wave_gemm<768>(A + (size_t)m0 * 768, 768, wT + (size_t)n0 * 768, 768, acc);
  int lane = threadIdx.x & 63, l15 = lane & 15, quad = lane >> 4;
  #pragma unroll
  for (int mt = 0; mt < 4; ++mt)
    #pragma unroll
    for (int nt = 0; nt < 4; ++nt)
      #pragma unroll
      for (int r = 0; r < 4; ++r) {
        int m = m0 + mt * 16 + quad * 4 + r;
        int n = n0 + nt * 16 + l15;
        float v = acc[mt][nt][r] + bias[n];
        v = 0.5f * v * (1.f + erff(v * 0.70710678f));
        out[(size_t)m * 3072 + n] = f2bf(v);
      }
}

// ---------------- FC2 GEMM + bias + residual -> fp32 out ----------------
__global__ __launch_bounds__(256) void gemm_fc2_k(const u16* __restrict__ A,
                                                  const u16* __restrict__ wT,
                                                  const float* __restrict__ bias,
                                                  const float* __restrict__ resid,
                                                  float* __restrict__ out) {
  int wave = threadIdx.x >> 6;
  int m0 = blockIdx.y * 128 + (wave & 1) * 64;
  int n0 = blockIdx.x * 128 + (wave >> 1) * 64;
  f4 acc[4][4];
  ZERO44(acc);
  wave_gemm<3072>(A + (size_t)m0 * 3072, 3072, wT + (size_t)n0 * 3072, 3072, acc);
  int lane = threadIdx.x & 63, l15 = lane & 15, quad = lane >> 4;
  #pragma unroll
  for (int mt = 0; mt < 4; ++mt)
    #pragma unroll
    for (int nt = 0; nt < 4; ++nt)
      #pragma unroll
      for (int r = 0; r < 4; ++r) {
        int m = m0 + mt * 16 + quad * 4 + r;
        int n = n0 + nt * 16 + l15;
        size_t idx = (size_t)m * 768 + n;
        out[idx] = acc[mt][nt][r] + bias[n] + resid[idx];
      }
}

// ---------------- attention pass 1: recipT[b][q][p] = 1/sum_h exp(s*scale) ----------------
__global__ __launch_bounds__(256) void attn_denom_k(const u16* __restrict__ Q,
                                                    const u16* __restrict__ Km,
                                                    float* __restrict__ recipT) {
  int qt = blockIdx.x, pt = blockIdx.y, b = blockIdx.z;
  int wave = threadIdx.x >> 6, lane = threadIdx.x & 63, l15 = lane & 15, quad = lane >> 4;
  __shared__ float red[4][64][64];  // 64 KB: [wave][q][p]
  f4 esum[4][4];
  ZERO44(esum);
  for (int h = wave; h < H_; h += 4) {
    const u16* Qp = Q + ((size_t)(b * H_ + h) * P_ + pt * 64) * HD_;
    const u16* Kp = Km + ((size_t)(b * H_ + h) * P_ + qt * 64) * HD_;
    f4 s[4][4];
    ZERO44(s);
    #pragma unroll
    for (int ks = 0; ks < 2; ++ks) {
      bf8 af[4], bf_[4];
      #pragma unroll
      for (int mt = 0; mt < 4; ++mt)
        af[mt] = *reinterpret_cast<const bf8*>(Qp + (size_t)(mt * 16 + l15) * 64 + ks * 32 + quad * 8);
      #pragma unroll
      for (int nt = 0; nt < 4; ++nt)
        bf_[nt] = *reinterpret_cast<const bf8*>(Kp + (size_t)(nt * 16 + l15) * 64 + ks * 32 + quad * 8);
      #pragma unroll
      for (int mt = 0; mt < 4; ++mt)
        #pragma unroll
        for (int nt = 0; nt < 4; ++nt)
          s[mt][nt] = mfma16(af[mt], bf_[nt], s[mt][nt]);
    }
    #pragma unroll
    for (int mt = 0; mt < 4; ++mt)
      #pragma unroll
      for (int nt = 0; nt < 4; ++nt)
        #pragma unroll
        for (int r = 0; r < 4; ++r)
          esum[mt][nt][r] += __expf(s[mt][nt][r] * SCALE_);
  }
  // store transposed [q][p] so the 4 regs (consecutive p) are a float4
  #pragma unroll
  for (int mt = 0; mt < 4; ++mt)
    #pragma unroll
    for (int nt = 0; nt < 4; ++nt)
      *reinterpret_cast<f4*>(&red[wave][nt * 16 + l15][mt * 16 + quad * 4]) = esum[mt][nt];
  __syncthreads();
  int q = threadIdx.x >> 2, pb = threadIdx.x & 3;
  size_t rbase = ((size_t)b * P_ + qt * 64 + q) * P_ + pt * 64 + pb * 16;
  #pragma unroll
  for (int j = 0; j < 4; ++j) {
    f4 ssum = *reinterpret_cast<const f4*>(&red[0][q][pb * 16 + j * 4]);
    #pragma unroll
    for (int w = 1; w < 4; ++w)
      ssum += *reinterpret_cast<const f4*>(&red[w][q][pb * 16 + j * 4]);
    f4 rc;
    #pragma unroll
    for (int c = 0; c < 4; ++c) rc[c] = 1.0f / ssum[c];
    *reinterpret_cast<f4*>(recipT + rbase + j * 4) = rc;
  }
}

// ---------------- attention pass 2: O = (exp(S*scale)*recip) @ V, + residual -> x2 ----------------
__global__ __launch_bounds__(256) void attn_out_k(const u16* __restrict__ Q,
                                                  const u16* __restrict__ Km,
                                                  const u16* __restrict__ Vt,
                                                  const float* __restrict__ recipT,
                                                  const float* __restrict__ xin,
                                                  float* __restrict__ x2) {
  int pt = blockIdx.x, h = blockIdx.y, b = blockIdx.z;
  int wave = threadIdx.x >> 6, lane = threadIdx.x & 63, l15 = lane & 15, quad = lane >> 4;
  __shared__ __align__(16) char smem[65536];
  u16* albuf = reinterpret_cast<u16*>(smem) + (size_t)wave * 4096;  // [p][q] bf16, per wave
  float(*redbuf)[64][64] = reinterpret_cast<float(*)[64][64]>(smem);

  const u16* Qp = Q + ((size_t)(b * H_ + h) * P_ + pt * 64) * HD_;
  const u16* Kbase = Km + (size_t)(b * H_ + h) * P_ * HD_;
  const u16* Vbase = Vt + (size_t)(b * H_ + h) * HD_ * P_;

  bf8 qf[4][2];
  #pragma unroll
  for (int mt = 0; mt < 4; ++mt)
    #pragma unroll
    for (int ks = 0; ks < 2; ++ks)
      qf[mt][ks] = *reinterpret_cast<const bf8*>(Qp + (size_t)(mt * 16 + l15) * 64 + ks * 32 + quad * 8);

  f4 oacc[4][4];
  ZERO44(oacc);

  for (int qt = wave; qt < P_ / 64; qt += 4) {
    f4 s[4][4];
    ZERO44(s);
    const u16* Kp = Kbase + (size_t)qt * 64 * 64;
    #pragma unroll
    for (int ks = 0; ks < 2; ++ks) {
      bf8 kf[4];
      #pragma unroll
      for (int nt = 0; nt < 4; ++nt)
        kf[nt] = *reinterpret_cast<const bf8*>(Kp + (size_t)(nt * 16 + l15) * 64 + ks * 32 + quad * 8);
      #pragma unroll
      for (int mt = 0; mt < 4; ++mt)
        #pragma unroll
        for (int nt = 0; nt < 4; ++nt)
          s[mt][nt] = mfma16(qf[mt][ks], kf[nt], s[mt][nt]);
    }
    // A = exp(s*scale) * recip, write to LDS in [p][q] layout (bf16)
    const float* rp = recipT + ((size_t)b * P_ + qt * 64) * P_ + (size_t)pt * 64;
    #pragma unroll
    for (int mt = 0; mt < 4; ++mt)
      #pragma unroll
      for (int nt = 0; nt < 4; ++nt) {
        f4 rv = *reinterpret_cast<const f4*>(rp + (size_t)(nt * 16 + l15) * P_ + mt * 16 + quad * 4);
        #pragma unroll
        for (int r = 0; r < 4; ++r) {
          float aval = __expf(s[mt][nt][r] * SCALE_) * rv[r];
          albuf[(mt * 16 + quad * 4 + r) * 64 + nt * 16 + l15] = f2bf(aval);
        }
      }
    // O += A @ V  (A from LDS, V^T rows from global)
    #pragma unroll
    for (int ks = 0; ks < 2; ++ks) {
      bf8 vf[4];
      #pragma unroll
      for (int nt = 0; nt < 4; ++nt)
        vf[nt] = *reinterpret_cast<const bf8*>(Vbase + (size_t)(nt * 16 + l15) * P_ + qt * 64 + ks * 32 + quad * 8);
      #pragma unroll
      for (int mt = 0; mt < 4; ++mt) {
        bf8 af = *reinterpret_cast<const bf8*>(albuf + (mt * 16 + l15) * 64 + ks * 32 + quad * 8);
        #pragma unroll
        for (int nt = 0; nt < 4; ++nt)
          oacc[mt][nt] = mfma16(af, vf[nt], oacc[mt][nt]);
      }
    }
  }
  __syncthreads();  // albuf dead; reuse smem as float reduction buffer
  #pragma unroll
  for (int mt = 0; mt < 4; ++mt)
    #pragma unroll
    for (int nt = 0; nt < 4; ++nt)
      #pragma unroll
      for (int r = 0; r < 4; ++r)
        redbuf[wave][mt * 16 + quad * 4 + r][nt * 16 + l15] = oacc[mt][nt][r];
  __syncthreads();
  int p = threadIdx.x >> 2, db = threadIdx.x & 3;
  size_t go = ((size_t)(b * P_ + pt * 64 + p)) * D_ + h * 64 + db * 16;
  #pragma unroll
  for (int j = 0; j < 4; ++j) {
    f4 v = *reinterpret_cast<const f4*>(&redbuf[0][p][db * 16 + j * 4]);
    #pragma unroll
    for (int w = 1; w < 4; ++w)
      v += *reinterpret_cast<const f4*>(&redbuf[w][p][db * 16 + j * 4]);
    f4 xv = *reinterpret_cast<const f4*>(xin + go + j * 4);
    *reinterpret_cast<f4*>(x2 + go + j * 4) = v + xv;
  }
}

extern "C" void kernel_launch(void* const* d_in, const int* in_sizes, int n_in,
                              void* d_out, int out_size, void* d_ws, size_t ws_size,
                              hipStream_t stream) {
  const float* x = (const float*)d_in[0];
  const float* ln1w = (const float*)d_in[1];
  const float* ln1b = (const float*)d_in[2];
  const float* wqkv = (const float*)d_in[3];
  const float* bqkv = (const float*)d_in[4];
  const float* ln2w = (const float*)d_in[5];
  const float* ln2b = (const float*)d_in[6];
  const float* wfc1 = (const float*)d_in[7];
  const float* bfc1 = (const float*)d_in[8];
  const float* wfc2 = (const float*)d_in[9];
  const float* bfc2 = (const float*)d_in[10];
  float* out = (float*)d_out;

  char* ws = (char*)d_ws;
  size_t off = 0;
  auto alloc = [&](size_t bytes) -> void* {
    void* p = ws + off;
    off += (bytes + 255) & ~(size_t)255;
    return p;
  };
  u16* hln = (u16*)alloc((size_t)8192 * 768 * 2);       // reused as hln2
  u16* wqkvT = (u16*)alloc((size_t)2304 * 768 * 2);
  u16* wfc1T = (u16*)alloc((size_t)3072 * 768 * 2);
  u16* wfc2T = (u16*)alloc((size_t)768 * 3072 * 2);
  u16* Qb = (u16*)alloc((size_t)B_ * H_ * P_ * HD_ * 2);
  u16* Kb = (u16*)alloc((size_t)B_ * H_ * P_ * HD_ * 2);
  u16* Vtb = (u16*)alloc((size_t)B_ * H_ * HD_ * P_ * 2);
  float* x2 = (float*)alloc((size_t)8192 * 768 * 4);
  float* recipT = (float*)alloc((size_t)B_ * P_ * P_ * 4);  // reused as fc1 output (g)
  u16* g = (u16*)recipT;

  tcast_k<<<dim3(72, 24), 256, 0, stream>>>(wqkv, wqkvT, 768, 2304);
  tcast_k<<<dim3(96, 24), 256, 0, stream>>>(wfc1, wfc1T, 768, 3072);
  tcast_k<<<dim3(24, 96), 256, 0, stream>>>(wfc2, wfc2T, 3072, 768);
  ln_k<<<8192, 256, 0, stream>>>(x, ln1w, ln1b, hln);
  gemm_qkv_k<<<dim3(18, 64), 256, 0, stream>>>(hln, wqkvT, bqkv, Qb, Kb, Vtb);
  attn_denom_k<<<dim3(32, 32, 4), 256, 0, stream>>>(Qb, Kb, recipT);
  attn_out_k<<<dim3(32, 12, 4), 256, 0, stream>>>(Qb, Kb, Vtb, recipT, x, x2);
  ln_k<<<8192, 256, 0, stream>>>(x2, ln2w, ln2b, hln);
  gemm_fc1_k<<<dim3(24, 64), 256, 0, stream>>>(hln, wfc1T, bfc1, g);
  gemm_fc2_k<<<dim3(6, 64), 256, 0, stream>>>(g, wfc2T, bfc2, x2, out);
}